// Round 1
// baseline (1897.223 us; speedup 1.0000x reference)
//
#include <hip/hip_runtime.h>
#include <math.h>

#define EPS_BN 1e-5f

// ---------------------------------------------------------------------------
// init: deg = 1 (self-loop), zero pool accumulators (ws is poisoned 0xAA)
// ---------------------------------------------------------------------------
__global__ __launch_bounds__(256) void k_init(float* deg, float* gsum, float* gcnt, int n) {
    int i = blockIdx.x * 256 + threadIdx.x;
    if (i < n) deg[i] = 1.0f;
    if (i < 64 * 64) gsum[i] = 0.0f;
    if (i < 64) gcnt[i] = 0.0f;
}

// deg[col[e]] += 1 over E edges
__global__ __launch_bounds__(256) void k_deg(const int* __restrict__ col, float* deg, int e) {
    int i = blockIdx.x * 256 + threadIdx.x;
    if (i < e) atomicAdd(&deg[col[i]], 1.0f);
}

// deg -> 1/sqrt(deg)  (deg >= 1 always, self-loop)
__global__ __launch_bounds__(256) void k_dinv(float* deg, int n) {
    int i = blockIdx.x * 256 + threadIdx.x;
    if (i < n) deg[i] = 1.0f / sqrtf(deg[i]);
}

// fold conv-bias + BN(eval) into per-feature scale/shift:
//   act(v) = relu(v*scale + shift), scale = g/sqrt(var+eps), shift = (b - m)*scale + beta
__global__ void k_params(const float* b1, const float* g1, const float* bb1, const float* m1, const float* v1,
                         const float* b2, const float* g2, const float* bb2, const float* m2, const float* v2,
                         float* sc1, float* sh1, float* sc2, float* sh2) {
    int t = threadIdx.x;
    if (t < 64) {
        float s1 = g1[t] / sqrtf(v1[t] + EPS_BN);
        sc1[t] = s1;
        sh1[t] = (b1[t] - m1[t]) * s1 + bb1[t];
        float s2 = g2[t] / sqrtf(v2[t] + EPS_BN);
        sc2[t] = s2;
        sh2[t] = (b2[t] - m2[t]) * s2 + bb2[t];
    }
}

// ---------------------------------------------------------------------------
// GEMM: out[n][64] = act(in[n][64]) @ W^T     (W is [64 out][64 in] row-major)
// 256 nodes / block; thread = (hg 0..3)*(ng 0..63): 4 nodes x 16 h-cols.
// W staged in LDS as float4, broadcast reads (all lanes same addr -> free).
// ---------------------------------------------------------------------------
template <bool ACT>
__global__ __launch_bounds__(256) void k_gemm(const float* __restrict__ in, const float* __restrict__ W,
                                              const float* __restrict__ scale, const float* __restrict__ shift,
                                              float* __restrict__ out, int n) {
    __shared__ float4 Wl[1024];  // [h][f4]
    __shared__ float4 scl[16], shl[16];
    const float4* W4 = (const float4*)W;
    for (int i = threadIdx.x; i < 1024; i += 256) Wl[i] = W4[i];
    if (ACT && threadIdx.x < 16) {
        scl[threadIdx.x] = ((const float4*)scale)[threadIdx.x];
        shl[threadIdx.x] = ((const float4*)shift)[threadIdx.x];
    }
    __syncthreads();

    int hg = threadIdx.x >> 6;  // wave-uniform
    int h0 = hg * 16;
    int ng = threadIdx.x & 63;
    int n0 = blockIdx.x * 256 + 4 * ng;

    float acc[4][16];
#pragma unroll
    for (int j = 0; j < 4; ++j)
#pragma unroll
        for (int k = 0; k < 16; ++k) acc[j][k] = 0.0f;

    const float4* in4 = (const float4*)in;
    bool valid[4];
#pragma unroll
    for (int j = 0; j < 4; ++j) valid[j] = (n0 + j) < n;

    for (int f4 = 0; f4 < 16; ++f4) {
        float4 sc, sh;
        if (ACT) { sc = scl[f4]; sh = shl[f4]; }
        float4 xv[4];
#pragma unroll
        for (int j = 0; j < 4; ++j) {
            float4 v = valid[j] ? in4[(n0 + j) * 16 + f4] : float4{0.f, 0.f, 0.f, 0.f};
            if (ACT) {
                v.x = fmaxf(v.x * sc.x + sh.x, 0.0f);
                v.y = fmaxf(v.y * sc.y + sh.y, 0.0f);
                v.z = fmaxf(v.z * sc.z + sh.z, 0.0f);
                v.w = fmaxf(v.w * sc.w + sh.w, 0.0f);
            }
            xv[j] = v;
        }
#pragma unroll
        for (int hh = 0; hh < 16; ++hh) {
            float4 w = Wl[(h0 + hh) * 16 + f4];
#pragma unroll
            for (int j = 0; j < 4; ++j) {
                acc[j][hh] += xv[j].x * w.x;
                acc[j][hh] += xv[j].y * w.y;
                acc[j][hh] += xv[j].z * w.z;
                acc[j][hh] += xv[j].w * w.w;
            }
        }
    }

    float4* out4 = (float4*)out;
#pragma unroll
    for (int j = 0; j < 4; ++j) {
        if (!valid[j]) continue;
#pragma unroll
        for (int q = 0; q < 4; ++q) {
            float4 o = {acc[j][4 * q], acc[j][4 * q + 1], acc[j][4 * q + 2], acc[j][4 * q + 3]};
            out4[(n0 + j) * 16 + (h0 >> 2) + q] = o;
        }
    }
}

// ---------------------------------------------------------------------------
// self-loop message doubles as the scatter-output initializer:
//   out[i][:] = h[i][:] * dinv[i]^2
// ---------------------------------------------------------------------------
__global__ __launch_bounds__(256) void k_self(const float* __restrict__ h, const float* __restrict__ dinv,
                                              float* __restrict__ out, int n) {
    int gid = blockIdx.x * 256 + threadIdx.x;
    int i = gid >> 4, q = gid & 15;
    if (i >= n) return;
    float d = dinv[i];
    d = d * d;
    float4 v = ((const float4*)h)[i * 16 + q];
    v.x *= d; v.y *= d; v.z *= d; v.w *= d;
    ((float4*)out)[i * 16 + q] = v;
}

// ---------------------------------------------------------------------------
// edge scatter: 16 lanes per edge; lane gathers one float4 of h[row],
// scales by dinv[row]*dinv[col], atomically adds into out[col].
// ---------------------------------------------------------------------------
__global__ __launch_bounds__(256) void k_scatter(const int* __restrict__ row, const int* __restrict__ col,
                                                 const float* __restrict__ dinv, const float* __restrict__ h,
                                                 float* out, int e) {
    int gid = blockIdx.x * 256 + threadIdx.x;
    int ei = gid >> 4, q = gid & 15;
    if (ei >= e) return;
    int r = row[ei], c = col[ei];
    float nrm = dinv[r] * dinv[c];
    float4 v = ((const float4*)h)[r * 16 + q];
    float* o = out + c * 64 + q * 4;
    atomicAdd(o + 0, v.x * nrm);
    atomicAdd(o + 1, v.y * nrm);
    atomicAdd(o + 2, v.z * nrm);
    atomicAdd(o + 3, v.w * nrm);
}

// ---------------------------------------------------------------------------
// pool: batch is SORTED. One wave per 64-node chunk, lane = feature.
// Accumulate in registers, flush one atomic per (graph-run, feature).
// Applies act2 = relu(v*sc2 + sh2) on the fly.
// ---------------------------------------------------------------------------
__global__ __launch_bounds__(256) void k_pool(const float* __restrict__ out2, const int* __restrict__ batch,
                                              const float* __restrict__ sc2, const float* __restrict__ sh2,
                                              float* gsum, float* gcnt, int n) {
    int gid = blockIdx.x * 256 + threadIdx.x;
    int h = gid & 63;
    int chunk = gid >> 6;
    int start = chunk * 64;
    if (start >= n) return;
    int end = min(start + 64, n);
    float s = sc2[h], b = sh2[h];
    int gcur = batch[start];  // wave-uniform
    float acc = 0.0f, cnt = 0.0f;
    for (int i = start; i < end; ++i) {
        int g = batch[i];
        if (g != gcur) {  // wave-uniform branch
            atomicAdd(&gsum[gcur * 64 + h], acc);
            if (h == 0) atomicAdd(&gcnt[gcur], cnt);
            acc = 0.0f; cnt = 0.0f; gcur = g;
        }
        float v = fmaxf(out2[i * 64 + h] * s + b, 0.0f);
        acc += v;
        cnt += 1.0f;
    }
    atomicAdd(&gsum[gcur * 64 + h], acc);
    if (h == 0) atomicAdd(&gcnt[gcur], cnt);
}

// ---------------------------------------------------------------------------
// MLP head: 64 graphs, one lane each. pooled = gsum/cnt; relu(lin1); lin2.
// ---------------------------------------------------------------------------
__global__ void k_mlp(const float* __restrict__ gsum, const float* __restrict__ gcnt,
                      const float* __restrict__ l1W, const float* __restrict__ l1b,
                      const float* __restrict__ l2W, const float* __restrict__ l2b,
                      float* __restrict__ outp) {
    int g = threadIdx.x;
    if (g >= 64) return;
    float inv = 1.0f / fmaxf(gcnt[g], 1.0f);
    float p[64];
#pragma unroll
    for (int hh = 0; hh < 64; ++hh) p[hh] = gsum[g * 64 + hh] * inv;
    float o = l2b[0];
    for (int j = 0; j < 32; ++j) {
        float a = l1b[j];
#pragma unroll
        for (int hh = 0; hh < 64; ++hh) a += p[hh] * l1W[j * 64 + hh];
        o += fmaxf(a, 0.0f) * l2W[j];
    }
    outp[g] = o;
}

// ---------------------------------------------------------------------------
extern "C" void kernel_launch(void* const* d_in, const int* in_sizes, int n_in,
                              void* d_out, int out_size, void* d_ws, size_t ws_size,
                              hipStream_t stream) {
    const float* x    = (const float*)d_in[0];
    const int*  ei    = (const int*)d_in[1];
    const int*  batch = (const int*)d_in[2];
    const float* W1   = (const float*)d_in[3];
    const float* b1   = (const float*)d_in[4];
    const float* W2   = (const float*)d_in[5];
    const float* b2   = (const float*)d_in[6];
    const float* bn1g = (const float*)d_in[7];
    const float* bn1b = (const float*)d_in[8];
    const float* bn1m = (const float*)d_in[9];
    const float* bn1v = (const float*)d_in[10];
    const float* bn2g = (const float*)d_in[11];
    const float* bn2b = (const float*)d_in[12];
    const float* bn2m = (const float*)d_in[13];
    const float* bn2v = (const float*)d_in[14];
    const float* l1W  = (const float*)d_in[15];
    const float* l1b  = (const float*)d_in[16];
    const float* l2W  = (const float*)d_in[17];
    const float* l2b  = (const float*)d_in[18];
    float* out = (float*)d_out;

    const int N = in_sizes[0] / 64;  // 100000
    const int E = in_sizes[1] / 2;   // 1000000
    const int* row  = ei;
    const int* colp = ei + E;

    // workspace layout (floats, all 16B-aligned)
    float* ws   = (float*)d_ws;
    float* deg  = ws;                       // N   (becomes dinv in place)
    float* sc1  = ws + N;                   // 64
    float* sh1  = sc1 + 64;
    float* sc2  = sh1 + 64;
    float* sh2  = sc2 + 64;
    float* gsum = sh2 + 64;                 // 64*64
    float* gcnt = gsum + 4096;              // 64
    float* bufA = gcnt + 64;                // N*64
    float* bufB = bufA + (size_t)N * 64;    // N*64

    int nb_n  = (N + 255) / 256;
    int nb_e  = (E + 255) / 256;
    int nb_n16 = (N * 16 + 255) / 256;
    int nb_e16 = (int)(((long)E * 16 + 255) / 256);
    int pool_threads = ((N + 63) / 64) * 64;
    int nb_pool = (pool_threads + 255) / 256;

    k_init<<<nb_n, 256, 0, stream>>>(deg, gsum, gcnt, N);
    k_deg<<<nb_e, 256, 0, stream>>>(colp, deg, E);
    k_dinv<<<nb_n, 256, 0, stream>>>(deg, N);
    k_params<<<1, 64, 0, stream>>>(b1, bn1g, bn1b, bn1m, bn1v,
                                   b2, bn2g, bn2b, bn2m, bn2v,
                                   sc1, sh1, sc2, sh2);
    // layer 1
    k_gemm<false><<<nb_n, 256, 0, stream>>>(x, W1, nullptr, nullptr, bufA, N);
    k_self<<<nb_n16, 256, 0, stream>>>(bufA, deg, bufB, N);
    k_scatter<<<nb_e16, 256, 0, stream>>>(row, colp, deg, bufA, bufB, E);
    // layer 2 (act1 fused into GEMM input read)
    k_gemm<true><<<nb_n, 256, 0, stream>>>(bufB, W2, sc1, sh1, bufA, N);
    k_self<<<nb_n16, 256, 0, stream>>>(bufA, deg, bufB, N);
    k_scatter<<<nb_e16, 256, 0, stream>>>(row, colp, deg, bufA, bufB, E);
    // pool + head
    k_pool<<<nb_pool, 256, 0, stream>>>(bufB, batch, sc2, sh2, gsum, gcnt, N);
    k_mlp<<<1, 64, 0, stream>>>(gsum, gcnt, l1W, l1b, l2W, l2b, out);
}

// Round 2
// 448.819 us; speedup vs baseline: 4.2271x; 4.2271x over previous
//
#include <hip/hip_runtime.h>
#include <math.h>

#define EPS_BN 1e-5f

// ---------------------------------------------------------------------------
// init: zero in-degree histogram + pool accumulators (ws is poisoned 0xAA)
// ---------------------------------------------------------------------------
__global__ __launch_bounds__(256) void k_init(int* icnt, float* gsum, float* gcnt, int n) {
    int i = blockIdx.x * 256 + threadIdx.x;
    if (i < n) icnt[i] = 0;
    if (i < 64 * 64) gsum[i] = 0.0f;
    if (i < 64) gcnt[i] = 0.0f;
}

// in-degree histogram over destinations
__global__ __launch_bounds__(256) void k_hist(const int* __restrict__ col, int* icnt, int e) {
    int i = blockIdx.x * 256 + threadIdx.x;
    if (i < e) atomicAdd(&icnt[col[i]], 1);
}

// dinv[i] = 1/sqrt(icnt[i] + 1)   (+1 = self-loop)
__global__ __launch_bounds__(256) void k_dinv(const int* __restrict__ icnt, float* dinv, int n) {
    int i = blockIdx.x * 256 + threadIdx.x;
    if (i < n) dinv[i] = rsqrtf((float)(icnt[i] + 1));
}

// fold conv-bias + BN(eval) into per-feature scale/shift
__global__ void k_params(const float* b1, const float* g1, const float* bb1, const float* m1, const float* v1,
                         const float* b2, const float* g2, const float* bb2, const float* m2, const float* v2,
                         float* sc1, float* sh1, float* sc2, float* sh2) {
    int t = threadIdx.x;
    if (t < 64) {
        float s1 = g1[t] / sqrtf(v1[t] + EPS_BN);
        sc1[t] = s1;
        sh1[t] = (b1[t] - m1[t]) * s1 + bb1[t];
        float s2 = g2[t] / sqrtf(v2[t] + EPS_BN);
        sc2[t] = s2;
        sh2[t] = (b2[t] - m2[t]) * s2 + bb2[t];
    }
}

// ---------------------------------------------------------------------------
// exclusive scan of icnt[N] -> offs[N+1] (3 kernels). Block = 256 thr x 4 elem.
// scan3 also zeros icnt so it can be reused as the fill cursor.
// ---------------------------------------------------------------------------
#define SCAN_EPB 1024

__global__ __launch_bounds__(256) void k_scan1(const int* __restrict__ icnt, int* part, int n) {
    __shared__ int sd[256];
    int base = blockIdx.x * SCAN_EPB;
    int s = 0;
#pragma unroll
    for (int j = 0; j < 4; ++j) {
        int idx = base + threadIdx.x * 4 + j;
        if (idx < n) s += icnt[idx];
    }
    sd[threadIdx.x] = s;
    __syncthreads();
    for (int off = 128; off > 0; off >>= 1) {
        if (threadIdx.x < off) sd[threadIdx.x] += sd[threadIdx.x + off];
        __syncthreads();
    }
    if (threadIdx.x == 0) part[blockIdx.x] = sd[0];
}

__global__ void k_scan2(int* part, int nb, int* offs, int n, int e) {
    if (threadIdx.x == 0) {
        int acc = 0;
        for (int i = 0; i < nb; ++i) { int v = part[i]; part[i] = acc; acc += v; }
        offs[n] = e;
    }
}

__global__ __launch_bounds__(256) void k_scan3(int* icnt, const int* __restrict__ part, int* offs, int n) {
    __shared__ int sd[256];
    int base = blockIdx.x * SCAN_EPB;
    int idx0 = base + threadIdx.x * 4;
    int v[4];
    int s = 0;
#pragma unroll
    for (int j = 0; j < 4; ++j) {
        int idx = idx0 + j;
        v[j] = (idx < n) ? icnt[idx] : 0;
        s += v[j];
    }
    sd[threadIdx.x] = s;
    __syncthreads();
    // Hillis-Steele inclusive scan
    for (int off = 1; off < 256; off <<= 1) {
        int mine = sd[threadIdx.x];
        int add = (threadIdx.x >= off) ? sd[threadIdx.x - off] : 0;
        __syncthreads();
        sd[threadIdx.x] = mine + add;
        __syncthreads();
    }
    int run = part[blockIdx.x] + sd[threadIdx.x] - s;  // exclusive prefix
#pragma unroll
    for (int j = 0; j < 4; ++j) {
        int idx = idx0 + j;
        if (idx < n) { offs[idx] = run; icnt[idx] = 0; }
        run += v[j];
    }
}

// scatter edge sources into CSR slots (icnt doubles as per-node cursor)
__global__ __launch_bounds__(256) void k_fill(const int* __restrict__ row, const int* __restrict__ col,
                                              const int* __restrict__ offs, int* icnt,
                                              int* csr_row, int e) {
    int i = blockIdx.x * 256 + threadIdx.x;
    if (i >= e) return;
    int c = col[i];
    int slot = offs[c] + atomicAdd(&icnt[c], 1);
    csr_row[slot] = row[i];
}

// ---------------------------------------------------------------------------
// GEMM: out[n][64] = act(in[n][64]) @ W^T   (unchanged from R1)
// ---------------------------------------------------------------------------
template <bool ACT>
__global__ __launch_bounds__(256) void k_gemm(const float* __restrict__ in, const float* __restrict__ W,
                                              const float* __restrict__ scale, const float* __restrict__ shift,
                                              float* __restrict__ out, int n) {
    __shared__ float4 Wl[1024];  // [h][f4]
    __shared__ float4 scl[16], shl[16];
    const float4* W4 = (const float4*)W;
    for (int i = threadIdx.x; i < 1024; i += 256) Wl[i] = W4[i];
    if (ACT && threadIdx.x < 16) {
        scl[threadIdx.x] = ((const float4*)scale)[threadIdx.x];
        shl[threadIdx.x] = ((const float4*)shift)[threadIdx.x];
    }
    __syncthreads();

    int hg = threadIdx.x >> 6;
    int h0 = hg * 16;
    int ng = threadIdx.x & 63;
    int n0 = blockIdx.x * 256 + 4 * ng;

    float acc[4][16];
#pragma unroll
    for (int j = 0; j < 4; ++j)
#pragma unroll
        for (int k = 0; k < 16; ++k) acc[j][k] = 0.0f;

    const float4* in4 = (const float4*)in;
    bool valid[4];
#pragma unroll
    for (int j = 0; j < 4; ++j) valid[j] = (n0 + j) < n;

    for (int f4 = 0; f4 < 16; ++f4) {
        float4 sc, sh;
        if (ACT) { sc = scl[f4]; sh = shl[f4]; }
        float4 xv[4];
#pragma unroll
        for (int j = 0; j < 4; ++j) {
            float4 v = valid[j] ? in4[(n0 + j) * 16 + f4] : float4{0.f, 0.f, 0.f, 0.f};
            if (ACT) {
                v.x = fmaxf(v.x * sc.x + sh.x, 0.0f);
                v.y = fmaxf(v.y * sc.y + sh.y, 0.0f);
                v.z = fmaxf(v.z * sc.z + sh.z, 0.0f);
                v.w = fmaxf(v.w * sc.w + sh.w, 0.0f);
            }
            xv[j] = v;
        }
#pragma unroll
        for (int hh = 0; hh < 16; ++hh) {
            float4 w = Wl[(h0 + hh) * 16 + f4];
#pragma unroll
            for (int j = 0; j < 4; ++j) {
                acc[j][hh] += xv[j].x * w.x;
                acc[j][hh] += xv[j].y * w.y;
                acc[j][hh] += xv[j].z * w.z;
                acc[j][hh] += xv[j].w * w.w;
            }
        }
    }

    float4* out4 = (float4*)out;
#pragma unroll
    for (int j = 0; j < 4; ++j) {
        if (!valid[j]) continue;
#pragma unroll
        for (int q = 0; q < 4; ++q) {
            float4 o = {acc[j][4 * q], acc[j][4 * q + 1], acc[j][4 * q + 2], acc[j][4 * q + 3]};
            out4[(n0 + j) * 16 + (h0 >> 2) + q] = o;
        }
    }
}

// ---------------------------------------------------------------------------
// CSR pull: out[i] = dinv[i]^2 * h[i] + sum_{k in in-edges(i)} dinv[r]*dinv[i]*h[r]
// 16 lanes per node, float4 per lane. No atomics; one coalesced write.
// ---------------------------------------------------------------------------
__global__ __launch_bounds__(256) void k_apply(const float* __restrict__ h, const float* __restrict__ dinv,
                                               const int* __restrict__ offs, const int* __restrict__ csr_row,
                                               float* __restrict__ out, int n) {
    int gid = blockIdx.x * 256 + threadIdx.x;
    int i = gid >> 4, q = gid & 15;
    if (i >= n) return;
    const float4* h4 = (const float4*)h;
    float di = dinv[i];
    float4 acc = h4[i * 16 + q];
    float dd = di * di;
    acc.x *= dd; acc.y *= dd; acc.z *= dd; acc.w *= dd;

    int k = offs[i], end = offs[i + 1];
    for (; k + 1 < end; k += 2) {
        int r0 = csr_row[k], r1 = csr_row[k + 1];
        float n0 = dinv[r0] * di, n1 = dinv[r1] * di;
        float4 v0 = h4[r0 * 16 + q];
        float4 v1 = h4[r1 * 16 + q];
        acc.x += v0.x * n0 + v1.x * n1;
        acc.y += v0.y * n0 + v1.y * n1;
        acc.z += v0.z * n0 + v1.z * n1;
        acc.w += v0.w * n0 + v1.w * n1;
    }
    if (k < end) {
        int r0 = csr_row[k];
        float n0 = dinv[r0] * di;
        float4 v0 = h4[r0 * 16 + q];
        acc.x += v0.x * n0;
        acc.y += v0.y * n0;
        acc.z += v0.z * n0;
        acc.w += v0.w * n0;
    }
    ((float4*)out)[i * 16 + q] = acc;
}

// ---------------------------------------------------------------------------
// pool: batch is SORTED. One wave per 64-node chunk, lane = feature.
// ---------------------------------------------------------------------------
__global__ __launch_bounds__(256) void k_pool(const float* __restrict__ out2, const int* __restrict__ batch,
                                              const float* __restrict__ sc2, const float* __restrict__ sh2,
                                              float* gsum, float* gcnt, int n) {
    int gid = blockIdx.x * 256 + threadIdx.x;
    int h = gid & 63;
    int chunk = gid >> 6;
    int start = chunk * 64;
    if (start >= n) return;
    int end = min(start + 64, n);
    float s = sc2[h], b = sh2[h];
    int gcur = batch[start];
    float acc = 0.0f, cnt = 0.0f;
    for (int i = start; i < end; ++i) {
        int g = batch[i];
        if (g != gcur) {
            atomicAdd(&gsum[gcur * 64 + h], acc);
            if (h == 0) atomicAdd(&gcnt[gcur], cnt);
            acc = 0.0f; cnt = 0.0f; gcur = g;
        }
        float v = fmaxf(out2[i * 64 + h] * s + b, 0.0f);
        acc += v;
        cnt += 1.0f;
    }
    atomicAdd(&gsum[gcur * 64 + h], acc);
    if (h == 0) atomicAdd(&gcnt[gcur], cnt);
}

// ---------------------------------------------------------------------------
// MLP head
// ---------------------------------------------------------------------------
__global__ void k_mlp(const float* __restrict__ gsum, const float* __restrict__ gcnt,
                      const float* __restrict__ l1W, const float* __restrict__ l1b,
                      const float* __restrict__ l2W, const float* __restrict__ l2b,
                      float* __restrict__ outp) {
    int g = threadIdx.x;
    if (g >= 64) return;
    float inv = 1.0f / fmaxf(gcnt[g], 1.0f);
    float p[64];
#pragma unroll
    for (int hh = 0; hh < 64; ++hh) p[hh] = gsum[g * 64 + hh] * inv;
    float o = l2b[0];
    for (int j = 0; j < 32; ++j) {
        float a = l1b[j];
#pragma unroll
        for (int hh = 0; hh < 64; ++hh) a += p[hh] * l1W[j * 64 + hh];
        o += fmaxf(a, 0.0f) * l2W[j];
    }
    outp[g] = o;
}

// ---------------------------------------------------------------------------
extern "C" void kernel_launch(void* const* d_in, const int* in_sizes, int n_in,
                              void* d_out, int out_size, void* d_ws, size_t ws_size,
                              hipStream_t stream) {
    const float* x    = (const float*)d_in[0];
    const int*  ei    = (const int*)d_in[1];
    const int*  batch = (const int*)d_in[2];
    const float* W1   = (const float*)d_in[3];
    const float* b1   = (const float*)d_in[4];
    const float* W2   = (const float*)d_in[5];
    const float* b2   = (const float*)d_in[6];
    const float* bn1g = (const float*)d_in[7];
    const float* bn1b = (const float*)d_in[8];
    const float* bn1m = (const float*)d_in[9];
    const float* bn1v = (const float*)d_in[10];
    const float* bn2g = (const float*)d_in[11];
    const float* bn2b = (const float*)d_in[12];
    const float* bn2m = (const float*)d_in[13];
    const float* bn2v = (const float*)d_in[14];
    const float* l1W  = (const float*)d_in[15];
    const float* l1b  = (const float*)d_in[16];
    const float* l2W  = (const float*)d_in[17];
    const float* l2b  = (const float*)d_in[18];
    float* out = (float*)d_out;

    const int N = in_sizes[0] / 64;  // 100000
    const int E = in_sizes[1] / 2;   // 1000000
    const int* row  = ei;
    const int* colp = ei + E;

    // workspace layout (all offsets multiple of 4 elems -> 16B aligned)
    int*   icnt = (int*)d_ws;                    // N      (histogram, then fill cursor)
    int*   offs = icnt + N;                      // N+4    (offs[N] = E)
    float* dinv = (float*)(offs + N + 4);        // N
    float* sc1  = dinv + N;                      // 64
    float* sh1  = sc1 + 64;
    float* sc2  = sh1 + 64;
    float* sh2  = sc2 + 64;
    float* gsum = sh2 + 64;                      // 4096
    float* gcnt = gsum + 4096;                   // 64
    int*   csr_row = (int*)(gcnt + 64);          // E
    float* bufA = (float*)(csr_row + E);         // N*64
    float* bufB = bufA + (size_t)N * 64;         // N*64

    int nb_n   = (N + 255) / 256;
    int nb_e   = (E + 255) / 256;
    int nb_n16 = (N * 16 + 255) / 256;
    int nb_scan = (N + SCAN_EPB - 1) / SCAN_EPB;
    int* part = offs;  // scan partials: temporarily use offs[0..nb_scan) before scan3 overwrites
    // NOTE: scan3 writes offs[idx] AFTER reading part[blockIdx.x]; ranges overlap!
    // Use a separate partials array placed after bufB instead.
    int* partials = (int*)(bufB + (size_t)N * 64);  // nb_scan ints
    (void)part;

    int pool_threads = ((N + 63) / 64) * 64;
    int nb_pool = (pool_threads + 255) / 256;

    // ---- CSR build (once) ----
    k_init<<<nb_n, 256, 0, stream>>>(icnt, gsum, gcnt, N);
    k_hist<<<nb_e, 256, 0, stream>>>(colp, icnt, E);
    k_dinv<<<nb_n, 256, 0, stream>>>(icnt, dinv, N);
    k_params<<<1, 64, 0, stream>>>(b1, bn1g, bn1b, bn1m, bn1v,
                                   b2, bn2g, bn2b, bn2m, bn2v,
                                   sc1, sh1, sc2, sh2);
    k_scan1<<<nb_scan, 256, 0, stream>>>(icnt, partials, N);
    k_scan2<<<1, 64, 0, stream>>>(partials, nb_scan, offs, N, E);
    k_scan3<<<nb_scan, 256, 0, stream>>>(icnt, partials, offs, N);
    k_fill<<<nb_e, 256, 0, stream>>>(row, colp, offs, icnt, csr_row, E);

    // ---- layer 1 ----
    k_gemm<false><<<nb_n, 256, 0, stream>>>(x, W1, nullptr, nullptr, bufA, N);
    k_apply<<<nb_n16, 256, 0, stream>>>(bufA, dinv, offs, csr_row, bufB, N);
    // ---- layer 2 (act1 fused into GEMM input read) ----
    k_gemm<true><<<nb_n, 256, 0, stream>>>(bufB, W2, sc1, sh1, bufA, N);
    k_apply<<<nb_n16, 256, 0, stream>>>(bufA, dinv, offs, csr_row, bufB, N);
    // ---- pool + head ----
    k_pool<<<nb_pool, 256, 0, stream>>>(bufB, batch, sc2, sh2, gsum, gcnt, N);
    k_mlp<<<1, 64, 0, stream>>>(gsum, gcnt, l1W, l1b, l2W, l2b, out);
}